// Round 2
// baseline (28.803 us; speedup 1.0000x reference)
//
#include <hip/hip_runtime.h>

// SplatGaussian2D round 2: LDS-free. Per-gaussian params precomputed into d_ws,
// read via wave-uniform (scalar-pipe) loads. Weight folded to exp2(Lb - q),
// q = (S0^2*log2e)*rx^2 + (S1^2*log2e)*ry^2, valid <=> q < 25*log2e.

constexpr int   BN      = 8192;
constexpr int   NG      = 2048;
constexpr float SMIN    = 1.0f / 30.0f;
constexpr float SSPAN   = (1.0f / 0.75f - 1.0f / 30.0f);   // S_MAX - S_MIN
constexpr float MUSCALE = 1.05f * 256.0f;                  // MU_BORDER * 0.5*W
constexpr float LOG2E   = 1.44269504088896341f;
constexpr float QTHRESH = 25.0f * 1.44269504088896341f;    // 36.067376
constexpr int   BLOCK   = 256;
constexpr int   GCHUNK  = 64;
constexpr int   NSPLIT  = NG / GCHUNK;                     // 32

__global__ __launch_bounds__(256) void splat_precompute(
    const float* __restrict__ xyz,  // [N,2]
    const float* __restrict__ opac, // [N]
    const float* __restrict__ scal, // [N,2]
    const float* __restrict__ rot,  // [N]
    float* __restrict__ gp)         // [N,8]
{
    const int g = blockIdx.x * 256 + threadIdx.x;
    if (g >= NG) return;
    const float mx = fminf(fmaxf(xyz[2 * g + 0], -1.0f), 1.0f) * MUSCALE;
    const float my = fminf(fmaxf(xyz[2 * g + 1], -1.0f), 1.0f) * MUSCALE;
    const float s0 = fminf(fmaxf(scal[2 * g + 0], 0.0f), 1.0f) * SSPAN + SMIN;
    const float s1 = fminf(fmaxf(scal[2 * g + 1], 0.0f), 1.0f) * SSPAN + SMIN;
    const float rr = rot[g];
    const float ang = (rr - floorf(rr)) * 6.283185307179586f;
    const float op  = fminf(fmaxf(opac[g], 0.0f), 1.0f);
    float4* o = reinterpret_cast<float4*>(gp + 8 * g);
    o[0] = make_float4(mx, my, cosf(ang), sinf(ang));
    o[1] = make_float4(s0 * s0 * LOG2E, s1 * s1 * LOG2E,
                       log2f(fmaxf(op, 1e-30f)), 0.0f);
}

__global__ __launch_bounds__(BLOCK) void splat_main(
    const float* __restrict__ xb,   // [B,2]
    const float* __restrict__ feat, // [N,9,3]
    const float* __restrict__ gp,   // [N,8]
    float* __restrict__ out)        // [B,3]
{
    const int tid = threadIdx.x;
    const int r   = blockIdx.x * BLOCK + tid;
    const float ax = xb[2 * r + 0] - 256.0f;
    const float ay = xb[2 * r + 1] - 256.0f;
    const int g0 = blockIdx.y * GCHUNK;

    float o0 = 0.0f, o1 = 0.0f, o2 = 0.0f;

    // prefetch-by-1 of the (uniform) param vectors
    float4 pa = *reinterpret_cast<const float4*>(gp + 8 * g0);
    float4 pb = *reinterpret_cast<const float4*>(gp + 8 * g0 + 4);

    for (int gi = 0; gi < GCHUNK; ++gi) {
        const int g = g0 + gi;
        float4 na, nb;
        if (gi + 1 < GCHUNK) {
            na = *reinterpret_cast<const float4*>(gp + 8 * (g + 1));
            nb = *reinterpret_cast<const float4*>(gp + 8 * (g + 1) + 4);
        }
        const float vx = ax - pa.x;
        const float vy = ay - pa.y;
        const float cs = pa.z, sn = pa.w;
        const float rx = fmaf(cs, vx, -sn * vy);
        const float ry = fmaf(sn, vx,  cs * vy);
        const float q  = fmaf(pb.x, rx * rx, pb.y * (ry * ry));
        const bool valid = q < QTHRESH;
        if (__any(valid)) {
            const float w  = valid ? exp2f(pb.z - q) : 0.0f;
            const float iv = rsqrtf(fmaxf(vx * vx + vy * vy, 1e-24f));
            const float s1v = rx * iv;          // sin(theta), exact
            const float c1v = ry * iv;          // cos(theta)
            const float s2v = 2.0f * s1v * c1v;
            const float c2v = fmaf(-2.0f * s1v, s1v, 1.0f);
            const float s3v = fmaf(s1v, c2v, c1v * s2v);
            const float c3v = fmaf(c1v, c2v, -s1v * s2v);
            const float s4v = 2.0f * s2v * c2v;
            const float c4v = fmaf(-2.0f * s2v, s2v, 1.0f);
            const float* __restrict__ fg = feat + g * 27;   // uniform base
            #pragma unroll
            for (int c = 0; c < 3; ++c) {
                float xc = fg[c];
                xc = fmaf(s1v, fg[3 + c],  xc);
                xc = fmaf(c1v, fg[6 + c],  xc);
                xc = fmaf(s2v, fg[9 + c],  xc);
                xc = fmaf(c2v, fg[12 + c], xc);
                xc = fmaf(s3v, fg[15 + c], xc);
                xc = fmaf(c3v, fg[18 + c], xc);
                xc = fmaf(s4v, fg[21 + c], xc);
                xc = fmaf(c4v, fg[24 + c], xc);
                // w * sigmoid(xc) = w / (1 + exp(-xc))
                const float e  = exp2f(-xc * LOG2E);
                const float wv = __fdividef(w, 1.0f + e);
                if (c == 0) o0 += wv; else if (c == 1) o1 += wv; else o2 += wv;
            }
        }
        pa = na; pb = nb;
    }

    atomicAdd(&out[3 * r + 0], o0);
    atomicAdd(&out[3 * r + 1], o1);
    atomicAdd(&out[3 * r + 2], o2);
}

extern "C" void kernel_launch(void* const* d_in, const int* in_sizes, int n_in,
                              void* d_out, int out_size, void* d_ws, size_t ws_size,
                              hipStream_t stream) {
    const float* xb   = (const float*)d_in[0];
    const float* xyz  = (const float*)d_in[1];
    const float* feat = (const float*)d_in[2];
    const float* opac = (const float*)d_in[3];
    const float* scal = (const float*)d_in[4];
    const float* rot  = (const float*)d_in[5];
    float* out = (float*)d_out;
    float* gp  = (float*)d_ws;    // NG*8 floats = 64 KB

    hipMemsetAsync(out, 0, (size_t)out_size * sizeof(float), stream);
    splat_precompute<<<dim3((NG + 255) / 256), dim3(256), 0, stream>>>(xyz, opac, scal, rot, gp);
    dim3 grid(BN / BLOCK, NSPLIT);
    splat_main<<<grid, dim3(BLOCK, 1, 1), 0, stream>>>(xb, feat, gp, out);
}